// Round 4
// baseline (200.474 us; speedup 1.0000x reference)
//
#include <hip/hip_runtime.h>
#include <hip/hip_bf16.h>
#include <stdint.h>

using bf16_t = __hip_bfloat16;
typedef __bf16 bf16x8 __attribute__((ext_vector_type(8)));
typedef float f32x4 __attribute__((ext_vector_type(4)));

// ---------------------------------------------------------------- helpers
__device__ __forceinline__ void async_lds16(const void* g, void* l) {
  // global -> LDS direct copy, 16B/lane. LDS dest = wave-uniform base +
  // lane*16 (m104/m108); global source is per-lane (m173).
  __builtin_amdgcn_global_load_lds(
      (const __attribute__((address_space(1))) void*)g,
      (__attribute__((address_space(3))) void*)l, 16, 0, 0);
}

__device__ __forceinline__ unsigned short f2bf_u16(float f) {
  __hip_bfloat16 h = __float2bfloat16(f);
  return __builtin_bit_cast(unsigned short, h);
}

// ---------------------------------------------------------------- convert x
__global__ __launch_bounds__(256) void convert_x_kernel(
    const float* __restrict__ x, bf16_t* __restrict__ xb) {
  size_t i = ((size_t)blockIdx.x * 256 + threadIdx.x) * 4;
  float4 v = *(const float4*)(x + i);
  ushort4 o;
  o.x = f2bf_u16(v.x);
  o.y = f2bf_u16(v.y);
  o.z = f2bf_u16(v.z);
  o.w = f2bf_u16(v.w);
  *(ushort4*)(xb + i) = o;
}

// ------------------------------------------------ convert + transpose W (3x)
__global__ __launch_bounds__(256) void convert_transpose_w_kernel(
    const float* __restrict__ Wq, const float* __restrict__ Wk,
    const float* __restrict__ Wv, bf16_t* __restrict__ wt) {
  __shared__ bf16_t tile[32][33];
  const float* W = (blockIdx.z == 0) ? Wq : (blockIdx.z == 1) ? Wk : Wv;
  bf16_t* WT = wt + (size_t)blockIdx.z * 1024 * 1024;
  const int tx = threadIdx.x & 31;
  const int ty = threadIdx.x >> 5;
  const int bx = blockIdx.x & 31;
  const int by = blockIdx.x >> 5;
  const int k0 = by * 32, n0 = bx * 32;
#pragma unroll
  for (int j = 0; j < 32; j += 8)
    tile[ty + j][tx] = __float2bfloat16(W[(size_t)(k0 + ty + j) * 1024 + n0 + tx]);
  __syncthreads();
#pragma unroll
  for (int j = 0; j < 32; j += 8)
    WT[(size_t)(n0 + ty + j) * 1024 + k0 + tx] = tile[tx][ty + j];
}

// ---------------------------------------------------------------- GEMM 256²
// C[M,N] = A[M,K] * BT[N,K]^T, both operands k-contiguous bf16.
// 256x256 tile, BK=64, 512 threads = 8 waves (2M x 4N), 128x64 per wave.
// LDS: 2 buffers x ( A[2 khalf][256 rows][32 k] + B same ) = 128 KB.
// 4 phases per K-step (kh,mh): {ds_read 4-8 b128; stage 1 half (2 gload_lds);
// barrier; lgkmcnt(0); setprio(1); 16 MFMA; setprio(0); barrier}.
// Stage schedule ph1..4 = [t+1:A-k1, t+1:B-k1, t+2:A-k0, t+2:B-k0]; one
// s_waitcnt vmcnt(4) per K-step (end of ph4) confirms ALL of step t+1
// (issued >=4 phases earlier). Ledger (in 2-call half units):
//   entry(t): 4 outstanding (t+1 kh0); +8 during t; vmcnt(4) retires the 8
//   oldest = all of t+1; leaves 4 = t+2 kh0. Region safety: t+2 kh0 targets
//   cur buffer regions whose last reads end at ph1/ph2 exit barriers.
// T2 swizzle (round-3, measured 0 conflicts): 16B slot s^((row>>1)&3) on the
// global source (LDS written linearly) and on the ds_read address.
// OUT_MODE: 2 = f32 row-major; 3 = QKV routing (Q,K bf16 row-major; V^T).
template <int OUT_MODE, bool CAUSAL_SKIP, bool KLIMIT, bool XCDSWZ>
__global__ __launch_bounds__(512, 2) void gemm256_kernel(
    const bf16_t* __restrict__ A, const bf16_t* __restrict__ BT,
    void* __restrict__ Cv, void* __restrict__ Cv2, void* __restrict__ Cv3,
    int M, int N, int K, int lda, int ldb, int ldc,
    long long aBatch, long long bBatch, long long cBatch) {
  int bx = blockIdx.x, by = blockIdx.y;
  if (XCDSWZ) {
    const int gx = gridDim.x;
    const int nwg = gx * gridDim.y;  // must be a multiple of 8
    const int id = by * gx + bx;
    const int cpx = nwg >> 3;
    const int swz = (id & 7) * cpx + (id >> 3);
    by = swz / gx;
    bx = swz % gx;
  }
  const int m0 = by * 256;
  const int n0 = bx * 256;
  if (CAUSAL_SKIP && bx > by) return;  // tile fully above causal diagonal
  A += (size_t)blockIdx.z * aBatch;
  BT += (size_t)blockIdx.z * bBatch;
  int nkt = K >> 6;
  if (KLIMIT) {
    int lim = (m0 + 256) >> 6;
    nkt = nkt < lim ? nkt : lim;
  }

  __shared__ bf16_t lsA[2 * 16384];  // 64 KB: [buf][kh][256][32]
  __shared__ bf16_t lsB[2 * 16384];  // 64 KB

  const int tid = threadIdx.x;
  const int wid = tid >> 6;
  const int lane = tid & 63;
  const int wm = wid >> 2;  // 0..1
  const int wn = wid & 3;   // 0..3

  // ---- staging addressing (pre-swizzled global column; LDS linear in tid)
  const int sr = tid >> 2;                        // row 0..127 of a half
  const int sswz = (tid & 3) ^ ((tid >> 3) & 3);  // T2 involution
  const bf16_t* gA0 = A + (size_t)(m0 + sr) * lda + sswz * 8;
  const bf16_t* gA1 = A + (size_t)(m0 + 128 + sr) * lda + sswz * 8;
  const bf16_t* gB0 = BT + (size_t)(n0 + sr) * ldb + sswz * 8;
  const bf16_t* gB1 = BT + (size_t)(n0 + 128 + sr) * ldb + sswz * 8;

  auto stageA = [&](int t, int kh) {
    bf16_t* d = lsA + ((t & 1) << 14) + (kh << 13) + (wid << 9);
    const size_t co = (size_t)(t << 6) + (kh << 5);
    async_lds16(gA0 + co, d);
    async_lds16(gA1 + co, d + 4096);
  };
  auto stageB = [&](int t, int kh) {
    bf16_t* d = lsB + ((t & 1) << 14) + (kh << 13) + (wid << 9);
    const size_t co = (size_t)(t << 6) + (kh << 5);
    async_lds16(gB0 + co, d);
    async_lds16(gB1 + co, d + 4096);
  };

  // ---- ds_read fragment addressing (swizzled k-slot)
  const int kswz = ((lane >> 4) ^ ((lane >> 1) & 3)) * 8;
  const int aRd = (wm * 128 + (lane & 15)) * 32 + kswz;
  const int bRd = (wn * 64 + (lane & 15)) * 32 + kswz;

  f32x4 acc[8][4];
  const f32x4 zero = {0.f, 0.f, 0.f, 0.f};
#pragma unroll
  for (int m = 0; m < 8; ++m)
#pragma unroll
    for (int n = 0; n < 4; ++n) acc[m][n] = zero;

  // ---- prologue: step0 all 4 halves + step1 kh0 halves; confirm step0
  stageA(0, 0);
  stageB(0, 0);
  stageA(0, 1);
  stageB(0, 1);
  if (nkt > 1) {
    stageA(1, 0);
    stageB(1, 0);
    asm volatile("s_waitcnt vmcnt(4)" ::: "memory");
  } else {
    asm volatile("s_waitcnt vmcnt(0)" ::: "memory");
  }
  __builtin_amdgcn_s_barrier();

  bf16x8 af[4], bfr[4];

#define PHASE_TAIL()                                      \
  __builtin_amdgcn_s_barrier();                           \
  asm volatile("s_waitcnt lgkmcnt(0)" ::: "memory");      \
  __builtin_amdgcn_sched_barrier(0);                      \
  __builtin_amdgcn_s_setprio(1);

#define MFMA16(mh)                                        \
  _Pragma("unroll") for (int mf = 0; mf < 4; ++mf)        \
      _Pragma("unroll") for (int nf = 0; nf < 4; ++nf)    \
          acc[(mh)*4 + mf][nf] = __builtin_amdgcn_mfma_f32_16x16x32_bf16( \
              af[mf], bfr[nf], acc[(mh)*4 + mf][nf], 0, 0, 0);

  for (int t = 0; t < nkt; ++t) {
    const bf16_t* bufA = lsA + ((t & 1) << 14);
    const bf16_t* bufB = lsB + ((t & 1) << 14);

    // ---- phase 1: (kh0, mh0) ; stage t+1:A-k1
#pragma unroll
    for (int nf = 0; nf < 4; ++nf)
      bfr[nf] = *(const bf16x8*)(bufB + (nf << 9) + bRd);
#pragma unroll
    for (int mf = 0; mf < 4; ++mf)
      af[mf] = *(const bf16x8*)(bufA + (mf << 9) + aRd);
    if (t + 1 < nkt) stageA(t + 1, 1);
    PHASE_TAIL()
    MFMA16(0)
    __builtin_amdgcn_s_setprio(0);
    __builtin_amdgcn_s_barrier();

    // ---- phase 2: (kh0, mh1) ; stage t+1:B-k1 ; bfr reused
#pragma unroll
    for (int mf = 0; mf < 4; ++mf)
      af[mf] = *(const bf16x8*)(bufA + ((mf + 4) << 9) + aRd);
    if (t + 1 < nkt) stageB(t + 1, 1);
    PHASE_TAIL()
    MFMA16(1)
    __builtin_amdgcn_s_setprio(0);
    __builtin_amdgcn_s_barrier();

    // ---- phase 3: (kh1, mh0) ; stage t+2:A-k0
#pragma unroll
    for (int nf = 0; nf < 4; ++nf)
      bfr[nf] = *(const bf16x8*)(bufB + 8192 + (nf << 9) + bRd);
#pragma unroll
    for (int mf = 0; mf < 4; ++mf)
      af[mf] = *(const bf16x8*)(bufA + 8192 + (mf << 9) + aRd);
    if (t + 2 < nkt) stageA(t + 2, 0);
    PHASE_TAIL()
    MFMA16(0)
    __builtin_amdgcn_s_setprio(0);
    __builtin_amdgcn_s_barrier();

    // ---- phase 4: (kh1, mh1) ; stage t+2:B-k0 ; boundary vmcnt
#pragma unroll
    for (int mf = 0; mf < 4; ++mf)
      af[mf] = *(const bf16x8*)(bufA + 8192 + ((mf + 4) << 9) + aRd);
    if (t + 2 < nkt) stageB(t + 2, 0);
    PHASE_TAIL()
    MFMA16(1)
    __builtin_amdgcn_s_setprio(0);
    if (t + 2 < nkt) {
      asm volatile("s_waitcnt vmcnt(4)" ::: "memory");  // all of t+1 resident
    } else if (t + 1 < nkt) {
      asm volatile("s_waitcnt vmcnt(0)" ::: "memory");  // tail drain
    }
    __builtin_amdgcn_s_barrier();
  }
#undef PHASE_TAIL
#undef MFMA16

  // ---- epilogue: C/D frag layout col=lane&15, row=(lane>>4)*4+j (m89/m91)
  const int erow = wm * 128 + (lane >> 4) * 4;
  const int ecol = wn * 64 + (lane & 15);
  if (OUT_MODE == 2) {
    float* C = (float*)Cv + (size_t)blockIdx.z * cBatch;
#pragma unroll
    for (int m = 0; m < 8; ++m)
#pragma unroll
      for (int n = 0; n < 4; ++n)
#pragma unroll
        for (int j = 0; j < 4; ++j) {
          int r = m0 + erow + m * 16 + j;
          int c = n0 + ecol + n * 16;
          C[(size_t)r * ldc + c] = acc[m][n][j];
        }
  } else {  // OUT_MODE == 3: QKV routing (regions are 1024-wide, 256-aligned)
    if (n0 < 2048) {
      bf16_t* C = (bf16_t*)((n0 < 1024) ? Cv : Cv2);
      const int cb0 = n0 & 1023;
#pragma unroll
      for (int m = 0; m < 8; ++m)
#pragma unroll
        for (int n = 0; n < 4; ++n)
#pragma unroll
          for (int j = 0; j < 4; ++j) {
            int r = m0 + erow + m * 16 + j;
            int c = cb0 + ecol + n * 16;
            C[(size_t)r * 1024 + c] = __float2bfloat16(acc[m][n][j]);
          }
    } else {
      // V^T batched: row r in [0,8192) -> b=r>>11, t=r&2047 ; VT[b][d][t]
      bf16_t* C = (bf16_t*)Cv3;
      const int d0 = n0 - 2048;
#pragma unroll
      for (int m = 0; m < 8; ++m)
#pragma unroll
        for (int n = 0; n < 4; ++n)
#pragma unroll
          for (int j = 0; j < 4; ++j) {
            int r = m0 + erow + m * 16 + j;
            int d = d0 + ecol + n * 16;
            int b = r >> 11, tt = r & 2047;
            C[((size_t)b * 1024 + d) * 2048 + tt] = __float2bfloat16(acc[m][n][j]);
          }
    }
  }
}

// ---------------------------------------------------------------- softmax
// One wave per (b,t) row; causal softmax of scale*S; P written bf16 in place
// (row fully register-staged first). Row pitch 2048 f32 = 4096 bf16.
// Causal trim: only quads it <= t>>8 are loaded/stored -- the PV GEMM reads
// row t only up to col (t>>8)*256+255 (its klimit window), rest untouched.
__global__ __launch_bounds__(256) void softmax_causal_kernel(float* __restrict__ S) {
  const int lane = threadIdx.x & 63;
  const int rg = blockIdx.x * 4 + (threadIdx.x >> 6);
  const int b = rg >> 11;
  const int t = rg & 2047;
  float* srow = S + (size_t)b * 2048 * 2048 + (size_t)t * 2048;
  const int qmax = t >> 8;  // quads 0..qmax are live

  float4 v[8];
#pragma unroll
  for (int it = 0; it < 8; ++it) {
    if (it <= qmax)
      v[it] = *(const float4*)(srow + (it * 64 + lane) * 4);
    else
      v[it] = make_float4(0.f, 0.f, 0.f, 0.f);
  }

  float mx = -3.0e38f;
#pragma unroll
  for (int it = 0; it < 8; ++it) {
    int s0 = (it * 64 + lane) * 4;
    if (s0 + 0 <= t) mx = fmaxf(mx, v[it].x);
    if (s0 + 1 <= t) mx = fmaxf(mx, v[it].y);
    if (s0 + 2 <= t) mx = fmaxf(mx, v[it].z);
    if (s0 + 3 <= t) mx = fmaxf(mx, v[it].w);
  }
#pragma unroll
  for (int off = 32; off > 0; off >>= 1) mx = fmaxf(mx, __shfl_xor(mx, off, 64));

  const float kMul = 0.03125f * 1.4426950408889634f;  // scale * log2(e)
  float p[8][4];
  float sum = 0.f;
#pragma unroll
  for (int it = 0; it < 8; ++it) {
    int s0 = (it * 64 + lane) * 4;
    float e0 = (s0 + 0 <= t) ? exp2f((v[it].x - mx) * kMul) : 0.f;
    float e1 = (s0 + 1 <= t) ? exp2f((v[it].y - mx) * kMul) : 0.f;
    float e2 = (s0 + 2 <= t) ? exp2f((v[it].z - mx) * kMul) : 0.f;
    float e3 = (s0 + 3 <= t) ? exp2f((v[it].w - mx) * kMul) : 0.f;
    p[it][0] = e0; p[it][1] = e1; p[it][2] = e2; p[it][3] = e3;
    sum += (e0 + e1) + (e2 + e3);
  }
#pragma unroll
  for (int off = 32; off > 0; off >>= 1) sum += __shfl_xor(sum, off, 64);
  const float inv = 1.f / sum;

  bf16_t* prow = (bf16_t*)srow;
#pragma unroll
  for (int it = 0; it < 8; ++it) {
    if (it <= qmax) {
      ushort4 o;
      o.x = f2bf_u16(p[it][0] * inv);
      o.y = f2bf_u16(p[it][1] * inv);
      o.z = f2bf_u16(p[it][2] * inv);
      o.w = f2bf_u16(p[it][3] * inv);
      *(ushort4*)(prow + (it * 64 + lane) * 4) = o;
    }
  }
}

// ---------------------------------------------------------------- launch
extern "C" void kernel_launch(void* const* d_in, const int* in_sizes, int n_in,
                              void* d_out, int out_size, void* d_ws, size_t ws_size,
                              hipStream_t stream) {
  (void)in_sizes; (void)n_in; (void)out_size;
  const float* x = (const float*)d_in[0];
  const float* Wq = (const float*)d_in[1];
  const float* Wk = (const float*)d_in[2];
  const float* Wv = (const float*)d_in[3];
  float* out = (float*)d_out;

  char* ws = (char*)d_ws;
  // batched layout (requires ~118 MiB):
  //   [0, 67.1M)        S_all (f32 [4][2048][2048]); xb (bf16 8192x1024)
  //                     aliases the front -- dead before S written
  //   [67.1M, 73.4M)    WT (bf16 [3072][1024], Wq^T|Wk^T|Wv^T stacked)
  //   [73.4M, 90.2M)    Q  (bf16 8192x1024)
  //   [90.2M, 107.0M)   K  (bf16 8192x1024)
  //   [107.0M, 123.7M)  VT (bf16 [4][1024][2048])
  const size_t NEED = 123731968;
  const bool batched = ws_size >= NEED;

  bf16_t* xb = (bf16_t*)ws;
  float* S;
  bf16_t *WT, *Qb, *Kb, *VT;
  if (batched) {
    S = (float*)ws;
    WT = (bf16_t*)(ws + 67108864);
    Qb = (bf16_t*)(ws + 73400320);
    Kb = (bf16_t*)(ws + 90177536);
    VT = (bf16_t*)(ws + 106954752);
  } else {
    S = (float*)ws;
    WT = (bf16_t*)(ws + 16777216);
    Qb = (bf16_t*)(ws + 16777216 + 6291456);
    Kb = Qb + 8388608;
    VT = Kb + 8388608;
  }

  // 1. conversions
  convert_x_kernel<<<8192, 256, 0, stream>>>(x, xb);
  convert_transpose_w_kernel<<<dim3(1024, 1, 3), 256, 0, stream>>>(Wq, Wk, Wv, WT);

  // 2. merged QKV projection: [8192,3072] = [8192,1024] x [3072,1024]^T
  //    384 blocks (32x12), XCD-swizzled (384 % 8 == 0)
  gemm256_kernel<3, false, false, true><<<dim3(12, 32, 1), 512, 0, stream>>>(
      xb, WT, Qb, Kb, VT, 8192, 3072, 1024, 1024, 1024, 0, 0, 0, 0);

  if (batched) {
    // 3. S = Q K^T, all batches (causal tile skip)
    gemm256_kernel<2, true, false, false><<<dim3(8, 8, 4), 512, 0, stream>>>(
        Qb, Kb, S, nullptr, nullptr, 2048, 2048, 1024, 1024, 1024, 2048,
        2097152LL, 2097152LL, 4194304LL);
    // 4. softmax -> P (bf16 in place, row pitch 4096 elems, causal-trimmed)
    softmax_causal_kernel<<<2048, 256, 0, stream>>>(S);
    // 5. O = P V, all batches (k-loop causal-limited)
    gemm256_kernel<2, false, true, false><<<dim3(4, 8, 4), 512, 0, stream>>>(
        (const bf16_t*)S, VT, out, nullptr, nullptr, 2048, 1024, 2048, 4096,
        2048, 1024, 8388608LL, 2097152LL, 2097152LL);
  } else {
    for (int b = 0; b < 4; ++b) {
      const size_t qoff = (size_t)b * 2048 * 1024;
      gemm256_kernel<2, true, false, false><<<dim3(8, 8, 1), 512, 0, stream>>>(
          Qb + qoff, Kb + qoff, S, nullptr, nullptr, 2048, 2048, 1024, 1024,
          1024, 2048, 0, 0, 0);
      softmax_causal_kernel<<<512, 256, 0, stream>>>(S);
      gemm256_kernel<2, false, true, false><<<dim3(4, 8, 1), 512, 0, stream>>>(
          (const bf16_t*)S, VT + qoff, out + qoff, nullptr, nullptr, 2048,
          1024, 2048, 4096, 2048, 1024, 0, 0, 0);
    }
  }
}

// Round 5
// 179.882 us; speedup vs baseline: 1.1145x; 1.1145x over previous
//
#include <hip/hip_runtime.h>
#include <hip/hip_bf16.h>
#include <stdint.h>

using bf16_t = __hip_bfloat16;
typedef __bf16 bf16x8 __attribute__((ext_vector_type(8)));
typedef float f32x4 __attribute__((ext_vector_type(4)));

// ---------------------------------------------------------------- helpers
__device__ __forceinline__ void async_lds16(const void* g, void* l) {
  // global -> LDS direct copy, 16B/lane. LDS dest = wave-uniform base +
  // lane*16 (m104/m108); global source is per-lane (m173).
  __builtin_amdgcn_global_load_lds(
      (const __attribute__((address_space(1))) void*)g,
      (__attribute__((address_space(3))) void*)l, 16, 0, 0);
}

__device__ __forceinline__ unsigned short f2bf_u16(float f) {
  __hip_bfloat16 h = __float2bfloat16(f);
  return __builtin_bit_cast(unsigned short, h);
}

__device__ __forceinline__ float bf2f(unsigned short u) {
  __hip_bfloat16 h = __builtin_bit_cast(__hip_bfloat16, u);
  return __bfloat162float(h);
}

// ------------------------------------------------ fused converts (x and W)
// blocks [0,8192): x f32 -> bf16 (4 elems/thread)
// blocks [8192,11264): W convert+transpose, 32x32 tiles
__global__ __launch_bounds__(256) void convert_all_kernel(
    const float* __restrict__ x, bf16_t* __restrict__ xb,
    const float* __restrict__ Wq, const float* __restrict__ Wk,
    const float* __restrict__ Wv, bf16_t* __restrict__ wt) {
  __shared__ bf16_t tile[32][33];
  const int bid = blockIdx.x;
  if (bid < 8192) {
    size_t i = ((size_t)bid * 256 + threadIdx.x) * 4;
    float4 v = *(const float4*)(x + i);
    ushort4 o;
    o.x = f2bf_u16(v.x);
    o.y = f2bf_u16(v.y);
    o.z = f2bf_u16(v.z);
    o.w = f2bf_u16(v.w);
    *(ushort4*)(xb + i) = o;
    return;
  }
  const int w = bid - 8192;            // 0..3071
  const int z = w >> 10;               // which W
  const int bxy = w & 1023;
  const float* W = (z == 0) ? Wq : (z == 1) ? Wk : Wv;
  bf16_t* WT = wt + (size_t)z * 1024 * 1024;
  const int tx = threadIdx.x & 31;
  const int ty = threadIdx.x >> 5;     // 0..7
  const int bx = bxy & 31;
  const int by = bxy >> 5;
  const int k0 = by * 32, n0 = bx * 32;
#pragma unroll
  for (int j = 0; j < 32; j += 8)
    tile[ty + j][tx] = __float2bfloat16(W[(size_t)(k0 + ty + j) * 1024 + n0 + tx]);
  __syncthreads();
#pragma unroll
  for (int j = 0; j < 32; j += 8)
    WT[(size_t)(n0 + ty + j) * 1024 + k0 + tx] = tile[tx][ty + j];
}

// ---------------------------------------------------------------- GEMM
// C[M,N] = A[M,K] * BT[N,K]^T, both operands k-contiguous bf16.
// 128(M) x 256(N) tile, BK=32, 512 threads = 8 waves (2M x 4N), 64x64/wave.
// 3 LDS buffers (72 KB -> 2 blocks/CU), counted-vmcnt pipeline: stage tile
// t+2 while computing tile t; boundary s_waitcnt vmcnt(3) guarantees tile
// t+1 landed. T2 swizzle: 16B slot s^((row>>1)&3) on the GLOBAL source (LDS
// written linearly by global_load_lds) and on the ds_read address — measured
// 0 bank conflicts (round 3). NO sched_barrier(0): compiler schedules
// ds_read->MFMA waits itself (m141: order-pinning regresses 40%).
// OUT_MODE: 2 = f32 row-major; 3 = QKV routing (Q,K bf16 row-major; V^T);
//           4 = bf16 row-major, pitch ldc, batched by cBatch.
template <int OUT_MODE, bool CAUSAL_SKIP, bool KLIMIT, bool XCDSWZ>
__global__ __launch_bounds__(512, 2) void gemm_pipe_kernel(
    const bf16_t* __restrict__ A, const bf16_t* __restrict__ BT,
    void* __restrict__ Cv, void* __restrict__ Cv2, void* __restrict__ Cv3,
    int M, int N, int K, int lda, int ldb, int ldc,
    long long aBatch, long long bBatch, long long cBatch) {
  int bx = blockIdx.x, by = blockIdx.y;
  if (XCDSWZ) {
    // bijective XCD swizzle (grid size must be a multiple of 8)
    const int gx = gridDim.x;
    const int nwg = gx * gridDim.y;
    const int id = by * gx + bx;
    const int cpx = nwg >> 3;
    const int swz = (id & 7) * cpx + (id >> 3);
    by = swz / gx;
    bx = swz % gx;
  }
  const int m0 = by * 128;
  const int n0 = bx * 256;
  if (CAUSAL_SKIP && 2 * bx > by) return;  // tile fully above causal diagonal
  A += (size_t)blockIdx.z * aBatch;
  BT += (size_t)blockIdx.z * bBatch;
  int nkt = K >> 5;
  if (KLIMIT) {
    int lim = (m0 + 128) >> 5;
    nkt = nkt < lim ? nkt : lim;
  }

  __shared__ bf16_t lsA[3 * 128 * 32];  // 24 KB, buffer stride 4096 elems
  __shared__ bf16_t lsB[3 * 256 * 32];  // 48 KB, buffer stride 8192 elems

  const int tid = threadIdx.x;
  const int wid = tid >> 6;
  const int lane = tid & 63;
  const int wm = wid >> 2;  // 0..1
  const int wn = wid & 3;   // 0..3

  // ---- stage source addressing (pre-swizzled global column)
  const int sr = tid >> 2;                  // row 0..127 within (half-)tile
  const int ss = tid & 3;                   // 16B slot 0..3
  const int sswz = ss ^ ((sr >> 1) & 3);    // T2 involution
  const bf16_t* gA = A + (size_t)(m0 + sr) * lda + sswz * 8;
  const bf16_t* gB0 = BT + (size_t)(n0 + sr) * ldb + sswz * 8;
  const bf16_t* gB1 = BT + (size_t)(n0 + 128 + sr) * ldb + sswz * 8;

  // ---- fragment read addressing (swizzled ds_read)
  const int kslot = (lane >> 4) ^ ((lane >> 1) & 3);
  const int abase = (wm * 64 + (lane & 15)) * 32 + kslot * 8;
  const int bbase = (wn * 64 + (lane & 15)) * 32 + kslot * 8;

  f32x4 acc[4][4];
  const f32x4 zero = {0.f, 0.f, 0.f, 0.f};
#pragma unroll
  for (int m = 0; m < 4; ++m)
#pragma unroll
    for (int n = 0; n < 4; ++n) acc[m][n] = zero;

  // ---- prologue: stage tiles 0 and 1; guarantee tile 0 resident
  async_lds16(gA, lsA + wid * 512);
  async_lds16(gB0, lsB + wid * 512);
  async_lds16(gB1, lsB + 4096 + wid * 512);
  if (nkt > 1) {
    async_lds16(gA + 32, lsA + 4096 + wid * 512);
    async_lds16(gB0 + 32, lsB + 8192 + wid * 512);
    async_lds16(gB1 + 32, lsB + 8192 + 4096 + wid * 512);
    asm volatile("s_waitcnt vmcnt(3)" ::: "memory");
  } else {
    asm volatile("s_waitcnt vmcnt(0)" ::: "memory");
  }
  __builtin_amdgcn_s_barrier();

  int cb = 0;  // current buffer index; stage target = (cb+2)%3
  for (int t = 0; t < nkt; ++t) {
    const bf16_t* bufA = lsA + cb * 4096;
    const bf16_t* bufB = lsB + cb * 8192;
    int sb = cb + 2;
    if (sb >= 3) sb -= 3;

    // ---------- phase 1: A frags + B frags 0,1 ; stage 2 calls ; 8 MFMA
    bf16x8 af[4], bfr[4];
#pragma unroll
    for (int mf = 0; mf < 4; ++mf)
      af[mf] = *(const bf16x8*)(bufA + abase + mf * 512);
    bfr[0] = *(const bf16x8*)(bufB + bbase);
    bfr[1] = *(const bf16x8*)(bufB + bbase + 512);
    if (t + 2 < nkt) {
      async_lds16(gA + (t + 2) * 32, lsA + sb * 4096 + wid * 512);
      async_lds16(gB0 + (t + 2) * 32, lsB + sb * 8192 + wid * 512);
    }
    __builtin_amdgcn_s_barrier();
    __builtin_amdgcn_s_setprio(1);
#pragma unroll
    for (int mf = 0; mf < 4; ++mf)
#pragma unroll
      for (int nf = 0; nf < 2; ++nf)
        acc[mf][nf] = __builtin_amdgcn_mfma_f32_16x16x32_bf16(
            af[mf], bfr[nf], acc[mf][nf], 0, 0, 0);
    __builtin_amdgcn_s_setprio(0);
    __builtin_amdgcn_s_barrier();

    // ---------- phase 2: B frags 2,3 ; stage 1 call ; vmcnt ; 8 MFMA
    bfr[2] = *(const bf16x8*)(bufB + bbase + 1024);
    bfr[3] = *(const bf16x8*)(bufB + bbase + 1536);
    if (t + 2 < nkt)
      async_lds16(gB1 + (t + 2) * 32, lsB + sb * 8192 + 4096 + wid * 512);
    if (t + 2 < nkt) {
      asm volatile("s_waitcnt vmcnt(3)" ::: "memory");  // tile t+1 resident
    } else if (t + 2 == nkt) {
      asm volatile("s_waitcnt vmcnt(0)" ::: "memory");  // drain last prefetch
    }
    __builtin_amdgcn_s_barrier();
    __builtin_amdgcn_s_setprio(1);
#pragma unroll
    for (int mf = 0; mf < 4; ++mf)
#pragma unroll
      for (int nf = 2; nf < 4; ++nf)
        acc[mf][nf] = __builtin_amdgcn_mfma_f32_16x16x32_bf16(
            af[mf], bfr[nf], acc[mf][nf], 0, 0, 0);
    __builtin_amdgcn_s_setprio(0);
    __builtin_amdgcn_s_barrier();

    cb = cb + 1;
    if (cb >= 3) cb -= 3;
  }

  // ---- epilogue: C/D frag layout col=lane&15, row=(lane>>4)*4+j (m89/m91)
  const int erow = wm * 64 + (lane >> 4) * 4;
  const int ecol = wn * 64 + (lane & 15);
  if (OUT_MODE == 2) {
    float* C = (float*)Cv + (size_t)blockIdx.z * cBatch;
#pragma unroll
    for (int m = 0; m < 4; ++m)
#pragma unroll
      for (int n = 0; n < 4; ++n)
#pragma unroll
        for (int j = 0; j < 4; ++j) {
          int r = m0 + erow + m * 16 + j;
          int c = n0 + ecol + n * 16;
          C[(size_t)r * ldc + c] = acc[m][n][j];
        }
  } else if (OUT_MODE == 4) {  // bf16 row-major, pitch ldc, batched
    bf16_t* C = (bf16_t*)Cv + (size_t)blockIdx.z * cBatch;
#pragma unroll
    for (int m = 0; m < 4; ++m)
#pragma unroll
      for (int n = 0; n < 4; ++n)
#pragma unroll
        for (int j = 0; j < 4; ++j) {
          int r = m0 + erow + m * 16 + j;
          int c = n0 + ecol + n * 16;
          C[(size_t)r * ldc + c] = __float2bfloat16(acc[m][n][j]);
        }
  } else {  // OUT_MODE == 3: QKV routing (n0 is 256-aligned, regions 1024-wide)
    if (n0 < 2048) {
      bf16_t* C = (bf16_t*)((n0 < 1024) ? Cv : Cv2);
      const int cb0 = n0 & 1023;
#pragma unroll
      for (int m = 0; m < 4; ++m)
#pragma unroll
        for (int n = 0; n < 4; ++n)
#pragma unroll
          for (int j = 0; j < 4; ++j) {
            int r = m0 + erow + m * 16 + j;
            int c = cb0 + ecol + n * 16;
            C[(size_t)r * 1024 + c] = __float2bfloat16(acc[m][n][j]);
          }
    } else {
      // V^T batched: row r in [0,8192) -> b=r>>11, t=r&2047 ; VT[b][d][t]
      bf16_t* C = (bf16_t*)Cv3;
      const int d0 = n0 - 2048;
#pragma unroll
      for (int m = 0; m < 4; ++m)
#pragma unroll
        for (int n = 0; n < 4; ++n)
#pragma unroll
          for (int j = 0; j < 4; ++j) {
            int r = m0 + erow + m * 16 + j;
            int d = d0 + ecol + n * 16;
            int b = r >> 11, tt = r & 2047;
            C[((size_t)b * 1024 + d) * 2048 + tt] = __float2bfloat16(acc[m][n][j]);
          }
    }
  }
}

// ---------------------------------------------------------------- softmax
// One wave per (b,t) row; S stored as bf16 (row pitch 4096 bf16). Causal
// softmax of scale*S; P written bf16 in place (row fully register-staged
// first). Causal trim: only 256-col quads it <= t>>8 are loaded/stored —
// the PV GEMM's klimit window reads exactly cols <= (t>>8)*256+255, and the
// trim zeroes the masked tail inside that window.
__global__ __launch_bounds__(256) void softmax_causal_kernel(bf16_t* __restrict__ Sb) {
  const int lane = threadIdx.x & 63;
  const int rg = blockIdx.x * 4 + (threadIdx.x >> 6);
  const int b = rg >> 11;
  const int t = rg & 2047;
  bf16_t* srow = Sb + (size_t)b * 8388608 + (size_t)t * 4096;
  const int qmax = t >> 8;  // quads 0..qmax are live

  float v[8][4];
#pragma unroll
  for (int it = 0; it < 8; ++it) {
    if (it <= qmax) {
      ushort4 u = *(const ushort4*)(srow + (it * 64 + lane) * 4);
      v[it][0] = bf2f(u.x);
      v[it][1] = bf2f(u.y);
      v[it][2] = bf2f(u.z);
      v[it][3] = bf2f(u.w);
    } else {
      v[it][0] = v[it][1] = v[it][2] = v[it][3] = 0.f;
    }
  }

  float mx = -3.0e38f;
#pragma unroll
  for (int it = 0; it < 8; ++it) {
    int s0 = (it * 64 + lane) * 4;
    if (s0 + 0 <= t) mx = fmaxf(mx, v[it][0]);
    if (s0 + 1 <= t) mx = fmaxf(mx, v[it][1]);
    if (s0 + 2 <= t) mx = fmaxf(mx, v[it][2]);
    if (s0 + 3 <= t) mx = fmaxf(mx, v[it][3]);
  }
#pragma unroll
  for (int off = 32; off > 0; off >>= 1) mx = fmaxf(mx, __shfl_xor(mx, off, 64));

  const float kMul = 0.03125f * 1.4426950408889634f;  // scale * log2(e)
  float p[8][4];
  float sum = 0.f;
#pragma unroll
  for (int it = 0; it < 8; ++it) {
    int s0 = (it * 64 + lane) * 4;
    float e0 = (s0 + 0 <= t) ? exp2f((v[it][0] - mx) * kMul) : 0.f;
    float e1 = (s0 + 1 <= t) ? exp2f((v[it][1] - mx) * kMul) : 0.f;
    float e2 = (s0 + 2 <= t) ? exp2f((v[it][2] - mx) * kMul) : 0.f;
    float e3 = (s0 + 3 <= t) ? exp2f((v[it][3] - mx) * kMul) : 0.f;
    p[it][0] = e0; p[it][1] = e1; p[it][2] = e2; p[it][3] = e3;
    sum += (e0 + e1) + (e2 + e3);
  }
#pragma unroll
  for (int off = 32; off > 0; off >>= 1) sum += __shfl_xor(sum, off, 64);
  const float inv = 1.f / sum;

#pragma unroll
  for (int it = 0; it < 8; ++it) {
    if (it <= qmax) {
      ushort4 o;
      o.x = f2bf_u16(p[it][0] * inv);
      o.y = f2bf_u16(p[it][1] * inv);
      o.z = f2bf_u16(p[it][2] * inv);
      o.w = f2bf_u16(p[it][3] * inv);
      *(ushort4*)(srow + (it * 64 + lane) * 4) = o;
    }
  }
}

// ---------------------------------------------------------------- launch
extern "C" void kernel_launch(void* const* d_in, const int* in_sizes, int n_in,
                              void* d_out, int out_size, void* d_ws, size_t ws_size,
                              hipStream_t stream) {
  (void)in_sizes; (void)n_in; (void)out_size;
  const float* x = (const float*)d_in[0];
  const float* Wq = (const float*)d_in[1];
  const float* Wk = (const float*)d_in[2];
  const float* Wv = (const float*)d_in[3];
  float* out = (float*)d_out;

  char* ws = (char*)d_ws;
  // batched layout (requires ~118 MiB):
  //   [0, 67.1M)        S_all (bf16, [4][2048] rows, pitch 4096 bf16 = 8KB;
  //                     only first half of region used); xb (bf16 8192x1024)
  //                     aliases the front -- dead before S written
  //   [67.1M, 73.4M)    WT (bf16 [3072][1024], Wq^T|Wk^T|Wv^T stacked)
  //   [73.4M, 90.2M)    Q  (bf16 8192x1024)
  //   [90.2M, 107.0M)   K  (bf16 8192x1024)
  //   [107.0M, 123.7M)  VT (bf16 [4][1024][2048])
  const size_t NEED = 123731968;
  const bool batched = ws_size >= NEED;

  bf16_t* xb = (bf16_t*)ws;
  bf16_t* Sb;
  bf16_t *WT, *Qb, *Kb, *VT;
  if (batched) {
    Sb = (bf16_t*)ws;
    WT = (bf16_t*)(ws + 67108864);
    Qb = (bf16_t*)(ws + 73400320);
    Kb = (bf16_t*)(ws + 90177536);
    VT = (bf16_t*)(ws + 106954752);
  } else {
    Sb = (bf16_t*)ws;
    WT = (bf16_t*)(ws + 16777216);
    Qb = (bf16_t*)(ws + 16777216 + 6291456);
    Kb = Qb + 8388608;
    VT = Kb + 8388608;
  }

  // 1. fused conversions (x -> bf16 ; W -> bf16 transposed stacked)
  convert_all_kernel<<<11264, 256, 0, stream>>>(x, xb, Wq, Wk, Wv, WT);

  // 2. merged QKV projection: [8192,3072] = [8192,1024] x [3072,1024]^T
  //    (768 blocks, XCD-swizzled: 768 % 8 == 0)
  gemm_pipe_kernel<3, false, false, true><<<dim3(12, 64, 1), 512, 0, stream>>>(
      xb, WT, Qb, Kb, VT, 8192, 3072, 1024, 1024, 1024, 0, 0, 0, 0);

  if (batched) {
    // 3. S = Q K^T, all batches (causal tile skip), bf16 out, pitch 4096
    gemm_pipe_kernel<4, true, false, false><<<dim3(8, 16, 4), 512, 0, stream>>>(
        Qb, Kb, Sb, nullptr, nullptr, 2048, 2048, 1024, 1024, 1024, 4096,
        2097152LL, 2097152LL, 8388608LL);
    // 4. softmax -> P (bf16 in place, causal-trimmed)
    softmax_causal_kernel<<<2048, 256, 0, stream>>>(Sb);
    // 5. O = P V, all batches (k-loop causal-limited)
    gemm_pipe_kernel<2, false, true, false><<<dim3(4, 16, 4), 512, 0, stream>>>(
        Sb, VT, out, nullptr, nullptr, 2048, 1024, 2048, 4096,
        2048, 1024, 8388608LL, 2097152LL, 2097152LL);
  } else {
    for (int b = 0; b < 4; ++b) {
      const size_t qoff = (size_t)b * 2048 * 1024;
      gemm_pipe_kernel<4, true, false, false><<<dim3(8, 16, 1), 512, 0, stream>>>(
          Qb + qoff, Kb + qoff, Sb, nullptr, nullptr, 2048, 2048, 1024, 1024,
          1024, 4096, 0, 0, 0);
      softmax_causal_kernel<<<512, 256, 0, stream>>>(Sb);
      gemm_pipe_kernel<2, false, true, false><<<dim3(4, 16, 1), 512, 0, stream>>>(
          Sb, VT + qoff, out + qoff, nullptr, nullptr, 2048,
          1024, 2048, 4096, 2048, 1024, 0, 0, 0);
    }
  }
}